// Round 4
// baseline (162.031 us; speedup 1.0000x reference)
//
#include <hip/hip_runtime.h>
#include <math.h>
#include <stdint.h>

#define HH 512
#define WW 512
#define BB 64
#define NP 13860

struct GaussW { float g[9]; };

__device__ __forceinline__ int reflect_idx(int i) {
    if (i < 0) i = -i;
    if (i > 511) i = 1022 - i;
    return i;
}

// One block = one (batch, 64x64 tile). Everything in LDS; no global scratch.
__global__ __launch_bounds__(256)
void fused_kernel(const float* __restrict__ V,
                  const float* __restrict__ P,
                  const float* __restrict__ pts,
                  float* __restrict__ out, GaussW gw) {
    __shared__ float VP[4][4];
    __shared__ unsigned int bm[80][4];   // splat bits: rows R0..R1, words W0..W0+3
    __shared__ unsigned int hd[80][4];   // horizontally dilated
    __shared__ unsigned int dl[72][4];   // fully dilated rows RD0..RD1
    __shared__ float vs[64][73];         // vertical-blur result (72 padded cols)

    const int b  = blockIdx.z;
    const int x0 = blockIdx.x * 64;
    const int y0 = blockIdx.y * 64;
    const int tid = threadIdx.y * 64 + threadIdx.x;

    const int R0  = (y0 - 8 > 0) ? y0 - 8 : 0;        // first splat row held
    const int R1  = (y0 + 71 < 511) ? y0 + 71 : 511;  // last splat row held
    const int W0  = (x0 == 0) ? 0 : (x0 / 32 - 1);    // first 32-col word held
    const int RD0 = (y0 - 4 > 0) ? y0 - 4 : 0;        // first dilated row held
    const int RD1 = (y0 + 67 < 511) ? y0 + 67 : 511;  // last dilated row held

    for (int e = tid; e < 80 * 4; e += 256) ((unsigned int*)bm)[e] = 0u;

    // VP = P @ V  (ascending j, fma chain)
    if (tid < 16) {
        const int i = tid >> 2, k = tid & 3;
        const float* Pb = P + b * 16;
        const float* Vb = V + b * 16;
        float a = __fmul_rn(Pb[i*4+0], Vb[0*4+k]);
        a = __fmaf_rn(Pb[i*4+1], Vb[1*4+k], a);
        a = __fmaf_rn(Pb[i*4+2], Vb[2*4+k], a);
        a = __fmaf_rn(Pb[i*4+3], Vb[3*4+k], a);
        VP[i][k] = a;
    }
    __syncthreads();

    // project all points of this batch; splat those inside our halo.
    // JAX quirk: invalid points get flat=-1, which .at[].set with NumPy
    // negative-index semantics WRAPS to the last pixel (511,511) — it is
    // NOT dropped. Replicate that.
    for (int n = tid; n < NP; n += 256) {
        const float4 p = ((const float4*)pts)[n];
        // tp[j] = sum_i p_i * VP[j][i]  (ascending i, fma chain)
        float tp0, tp1, tp3;
        {
            float a = __fmul_rn(p.x, VP[0][0]);
            a = __fmaf_rn(p.y, VP[0][1], a);
            a = __fmaf_rn(p.z, VP[0][2], a);
            a = __fmaf_rn(p.w, VP[0][3], a);
            tp0 = a;
        }
        {
            float a = __fmul_rn(p.x, VP[1][0]);
            a = __fmaf_rn(p.y, VP[1][1], a);
            a = __fmaf_rn(p.z, VP[1][2], a);
            a = __fmaf_rn(p.w, VP[1][3], a);
            tp1 = a;
        }
        {
            float a = __fmul_rn(p.x, VP[3][0]);
            a = __fmaf_rn(p.y, VP[3][1], a);
            a = __fmaf_rn(p.z, VP[3][2], a);
            a = __fmaf_rn(p.w, VP[3][3], a);
            tp3 = a;
        }
        const float w = tp3;
        const float x = (w != 0.f) ? (tp0 / w) : tp0;
        const float y = (w != 0.f) ? (tp1 / w) : tp1;
        // (x+1)*0.5*512: power-of-two scales are exact -> single rounding at add
        const float sxf = rintf(__fmul_rn(__fmul_rn(__fadd_rn(x, 1.f), 0.5f), 512.f));
        const float tmp = __fmul_rn(__fadd_rn(y, 1.f), 0.5f);
        const float syf = rintf(__fmul_rn(__fsub_rn(1.f, tmp), 512.f));
        int sx, sy;
        if (sxf >= 0.f && sxf < 512.f && syf >= 0.f && syf < 512.f) {
            sx = (int)sxf; sy = (int)syf;
        } else {
            sx = 511; sy = 511;   // flat=-1 wraps to last pixel
        }
        const int wj = (sx >> 5) - W0;
        if (sy >= R0 && sy <= R1 && wj >= 0 && wj < 4)
            atomicOr(&bm[sy - R0][wj], 1u << (sx & 31));
    }
    __syncthreads();

    // horizontal dilation (+-4) via bit shifts; word edges beyond halo are
    // only wrong within 4 cols of the halo edge, which are never read.
    const int NR = R1 - R0 + 1;
    for (int e = tid; e < NR * 4; e += 256) {
        const int r = e >> 2, j = e & 3;
        const unsigned int w  = bm[r][j];
        const unsigned int wl = (j > 0) ? bm[r][j-1] : 0u;
        const unsigned int wr = (j < 3) ? bm[r][j+1] : 0u;
        unsigned int h = w;
#pragma unroll
        for (int k = 1; k <= 4; ++k) {
            h |= (w << k) | (wl >> (32 - k));
            h |= (w >> k) | (wr << (32 - k));
        }
        hd[r][j] = h;
    }
    __syncthreads();

    // vertical dilation (+-4), clamped at image borders (== -inf SAME pad)
    const int ND = RD1 - RD0 + 1;
    for (int e = tid; e < ND * 4; e += 256) {
        const int r = RD0 + (e >> 2), j = e & 3;
        const int lo = (r - 4 > 0) ? r - 4 : 0;
        const int hi = (r + 4 < 511) ? r + 4 : 511;
        unsigned int acc = 0u;
        for (int rr = lo; rr <= hi; ++rr) acc |= hd[rr - R0][j];
        dl[r - RD0][j] = acc;
    }
    __syncthreads();

    // vertical 9-tap blur (reference conv order: H axis first), reflect pad
    for (int e = tid; e < 64 * 72; e += 256) {
        const int yy = e / 72;
        const int xc = e - yy * 72;
        const int col = reflect_idx(x0 + xc - 4);
        const int wj  = (col >> 5) - W0;
        const int bsh = col & 31;
        float acc = 0.f;
#pragma unroll
        for (int dy = 0; dy < 9; ++dy) {
            const int r = reflect_idx(y0 + yy + dy - 4);
            const float val = ((dl[r - RD0][wj] >> bsh) & 1u) ? 255.f : 0.f;
            acc = __fmaf_rn(gw.g[dy], val, acc);
        }
        vs[yy][xc] = acc;
    }
    __syncthreads();

    // horizontal 9-tap + threshold + 3-channel broadcast store
    const int tx = threadIdx.x;
    for (int yy = threadIdx.y; yy < 64; yy += 4) {
        float acc = 0.f;
#pragma unroll
        for (int dx = 0; dx < 9; ++dx)
            acc = __fmaf_rn(gw.g[dx], vs[yy][tx + dx], acc);
        const float m = (rintf(acc) > 100.f) ? 1.f : 0.f;
        const int yq = y0 + yy, xq = x0 + tx;
        float* o = out + ((size_t)(b * 3) * HH + yq) * WW + xq;
        o[0]                   = m;
        o[(size_t)HH * WW]     = m;
        o[(size_t)2 * HH * WW] = m;
    }
}

// ---------------------------------------------------------------- launch ---
extern "C" void kernel_launch(void* const* d_in, const int* in_sizes, int n_in,
                              void* d_out, int out_size, void* d_ws, size_t ws_size,
                              hipStream_t stream) {
    const float* V   = (const float*)d_in[0];
    const float* P   = (const float*)d_in[1];
    const float* pts = (const float*)d_in[2];
    float* out = (float*)d_out;
    (void)d_ws; (void)ws_size;   // no scratch used

    // Gaussian weights, replicating numpy f64 computation incl. pairwise sum
    const double sigma = 0.3 * ((9 - 1) * 0.5 - 1.0) + 0.8;
    double gd[9];
    for (int i = 0; i < 9; ++i) {
        const double t = ((double)i - 4.0) / sigma;
        gd[i] = exp(-0.5 * (t * t));
    }
    double s = ((gd[0] + gd[1]) + (gd[2] + gd[3])) + ((gd[4] + gd[5]) + (gd[6] + gd[7]));
    s += gd[8];
    GaussW gw;
    for (int i = 0; i < 9; ++i) gw.g[i] = (float)(gd[i] / s);

    fused_kernel<<<dim3(8, 8, BB), dim3(64, 4), 0, stream>>>(V, P, pts, out, gw);
}

// Round 5
// 113.687 us; speedup vs baseline: 1.4252x; 1.4252x over previous
//
#include <hip/hip_runtime.h>
#include <math.h>
#include <stdint.h>

#define HH 512
#define WW 512
#define BB 64
#define NP 13860
#define WPR 16                       // 32-bit words per image row
#define IMG_WORDS (BB * HH * WPR)    // 2 MB bit-image for all batches

struct GaussW { float g[9]; };

__device__ __forceinline__ int reflect_idx(int i) {
    if (i < 0) i = -i;
    if (i > 511) i = 1022 - i;
    return i;
}

// ---------------------------------------------------------------- splat ----
// One thread = one (point, batch). 887k projections total (vs 56.7M before).
__global__ __launch_bounds__(256)
void splat_kernel(const float* __restrict__ V,
                  const float* __restrict__ P,
                  const float* __restrict__ pts,
                  unsigned int* __restrict__ gbm) {
    __shared__ float VP[4][4];
    const int b = blockIdx.y;
    const int t = threadIdx.x;
    if (t < 16) {
        const int i = t >> 2, k = t & 3;
        const float* Pb = P + b * 16;
        const float* Vb = V + b * 16;
        float a = __fmul_rn(Pb[i*4+0], Vb[0*4+k]);
        a = __fmaf_rn(Pb[i*4+1], Vb[1*4+k], a);
        a = __fmaf_rn(Pb[i*4+2], Vb[2*4+k], a);
        a = __fmaf_rn(Pb[i*4+3], Vb[3*4+k], a);
        VP[i][k] = a;
    }
    __syncthreads();
    const int n = blockIdx.x * 256 + t;
    if (n >= NP) return;
    const float4 p = ((const float4*)pts)[n];
    float tp0, tp1, tp3;
    {
        float a = __fmul_rn(p.x, VP[0][0]);
        a = __fmaf_rn(p.y, VP[0][1], a);
        a = __fmaf_rn(p.z, VP[0][2], a);
        a = __fmaf_rn(p.w, VP[0][3], a);
        tp0 = a;
    }
    {
        float a = __fmul_rn(p.x, VP[1][0]);
        a = __fmaf_rn(p.y, VP[1][1], a);
        a = __fmaf_rn(p.z, VP[1][2], a);
        a = __fmaf_rn(p.w, VP[1][3], a);
        tp1 = a;
    }
    {
        float a = __fmul_rn(p.x, VP[3][0]);
        a = __fmaf_rn(p.y, VP[3][1], a);
        a = __fmaf_rn(p.z, VP[3][2], a);
        a = __fmaf_rn(p.w, VP[3][3], a);
        tp3 = a;
    }
    const float w = tp3;
    const float x = (w != 0.f) ? (tp0 / w) : tp0;
    const float y = (w != 0.f) ? (tp1 / w) : tp1;
    const float sxf = rintf(__fmul_rn(__fmul_rn(__fadd_rn(x, 1.f), 0.5f), 512.f));
    const float tmp = __fmul_rn(__fadd_rn(y, 1.f), 0.5f);
    const float syf = rintf(__fmul_rn(__fsub_rn(1.f, tmp), 512.f));
    int sx, sy;
    if (sxf >= 0.f && sxf < 512.f && syf >= 0.f && syf < 512.f) {
        sx = (int)sxf; sy = (int)syf;
    } else {
        sx = 511; sy = 511;   // JAX: flat=-1 wraps to last pixel, not dropped
    }
    atomicOr(&gbm[(b * HH + sy) * WPR + (sx >> 5)], 1u << (sx & 31));
}

// ------------------- tile kernel: dilate + blur + threshold + store --------
// One block = one (batch, 64x64 tile); bitmap halo loaded from global.
__global__ __launch_bounds__(256)
void tile_kernel(const unsigned int* __restrict__ gbm,
                 float* __restrict__ out, GaussW gw) {
    __shared__ unsigned int bm[80][4];   // splat bits, rows R0..R1, words W0..W0+3
    __shared__ unsigned int hd[80][4];   // horizontally dilated
    __shared__ unsigned int dl[72][4];   // fully dilated, rows RD0..RD1
    __shared__ float vs[64][73];         // vertical-blur result (72 padded cols)

    const int b  = blockIdx.z;
    const int x0 = blockIdx.x * 64;
    const int y0 = blockIdx.y * 64;
    const int tid = threadIdx.y * 16 + threadIdx.x;

    const int R0  = (y0 - 8 > 0) ? y0 - 8 : 0;
    const int R1  = (y0 + 71 < 511) ? y0 + 71 : 511;
    const int W0  = (x0 == 0) ? 0 : (x0 / 32 - 1);
    const int RD0 = (y0 - 4 > 0) ? y0 - 4 : 0;
    const int RD1 = (y0 + 67 < 511) ? y0 + 67 : 511;
    const int NR  = R1 - R0 + 1;

    // load bitmap halo (rows R0..R1, words W0..W0+3; OOB words -> 0)
    const unsigned int* gb = gbm + b * HH * WPR;
    for (int e = tid; e < 80 * 4; e += 256) {
        const int r = e >> 2, j = e & 3;
        unsigned int v = 0u;
        if (r < NR && W0 + j < WPR) v = gb[(R0 + r) * WPR + (W0 + j)];
        bm[r][j] = v;
    }
    __syncthreads();

    // horizontal dilation (+-4) via bit shifts
    for (int e = tid; e < NR * 4; e += 256) {
        const int r = e >> 2, j = e & 3;
        const unsigned int w  = bm[r][j];
        const unsigned int wl = (j > 0) ? bm[r][j-1] : 0u;
        const unsigned int wr = (j < 3) ? bm[r][j+1] : 0u;
        unsigned int h = w;
#pragma unroll
        for (int k = 1; k <= 4; ++k) {
            h |= (w << k) | (wl >> (32 - k));
            h |= (w >> k) | (wr << (32 - k));
        }
        hd[r][j] = h;
    }
    __syncthreads();

    // vertical dilation (+-4), clamped at image borders (== -inf SAME pad)
    const int ND = RD1 - RD0 + 1;
    for (int e = tid; e < ND * 4; e += 256) {
        const int r = RD0 + (e >> 2), j = e & 3;
        const int lo = (r - 4 > 0) ? r - 4 : 0;
        const int hi = (r + 4 < 511) ? r + 4 : 511;
        unsigned int acc = 0u;
        for (int rr = lo; rr <= hi; ++rr) acc |= hd[rr - R0][j];
        dl[r - RD0][j] = acc;
    }
    __syncthreads();

    // vertical 9-tap blur (reference conv order: H axis first), reflect pad
    for (int e = tid; e < 64 * 72; e += 256) {
        const int yy = e / 72;
        const int xc = e - yy * 72;
        const int col = reflect_idx(x0 + xc - 4);
        const int wj  = (col >> 5) - W0;
        const int bsh = col & 31;
        float acc = 0.f;
#pragma unroll
        for (int dy = 0; dy < 9; ++dy) {
            const int r = reflect_idx(y0 + yy + dy - 4);
            const float val = ((dl[r - RD0][wj] >> bsh) & 1u) ? 255.f : 0.f;
            acc = __fmaf_rn(gw.g[dy], val, acc);
        }
        vs[yy][xc] = acc;
    }
    __syncthreads();

    // horizontal 9-tap + threshold; 4 cols/thread -> float4 stores x3 channels
    const int c0 = threadIdx.x * 4;
#pragma unroll
    for (int k = 0; k < 4; ++k) {
        const int yy = threadIdx.y + 16 * k;
        float4 mq;
        float* mp = (float*)&mq;
#pragma unroll
        for (int q = 0; q < 4; ++q) {
            float acc = 0.f;
#pragma unroll
            for (int dx = 0; dx < 9; ++dx)
                acc = __fmaf_rn(gw.g[dx], vs[yy][c0 + q + dx], acc);
            mp[q] = (rintf(acc) > 100.f) ? 1.f : 0.f;
        }
        const int yq = y0 + yy, xq = x0 + c0;
        float* o = out + ((size_t)(b * 3) * HH + yq) * WW + xq;
        *(float4*)(o)                       = mq;
        *(float4*)(o + (size_t)HH * WW)     = mq;
        *(float4*)(o + (size_t)2 * HH * WW) = mq;
    }
}

// ---------------------------------------------------------------- launch ---
extern "C" void kernel_launch(void* const* d_in, const int* in_sizes, int n_in,
                              void* d_out, int out_size, void* d_ws, size_t ws_size,
                              hipStream_t stream) {
    const float* V   = (const float*)d_in[0];
    const float* P   = (const float*)d_in[1];
    const float* pts = (const float*)d_in[2];
    float* out = (float*)d_out;
    unsigned int* gbm = (unsigned int*)d_ws;   // 2 MB bit-image

    hipMemsetAsync(gbm, 0, IMG_WORDS * sizeof(unsigned int), stream);

    // Gaussian weights, replicating numpy f64 computation incl. pairwise sum
    const double sigma = 0.3 * ((9 - 1) * 0.5 - 1.0) + 0.8;
    double gd[9];
    for (int i = 0; i < 9; ++i) {
        const double t = ((double)i - 4.0) / sigma;
        gd[i] = exp(-0.5 * (t * t));
    }
    double s = ((gd[0] + gd[1]) + (gd[2] + gd[3])) + ((gd[4] + gd[5]) + (gd[6] + gd[7]));
    s += gd[8];
    GaussW gw;
    for (int i = 0; i < 9; ++i) gw.g[i] = (float)(gd[i] / s);

    splat_kernel<<<dim3((NP + 255) / 256, BB), 256, 0, stream>>>(V, P, pts, gbm);
    tile_kernel<<<dim3(8, 8, BB), dim3(16, 16), 0, stream>>>(gbm, out, gw);
}